// Round 7
// baseline (274.538 us; speedup 1.0000x reference)
//
#include <hip/hip_runtime.h>

// Workspace layout (float offsets)
#define WS_M      0        // Mrow[r*128+p] = M[p][r] (p-padded 100->128 w/ zeros), 12800 floats
#define WS_K      12800    // K[c][a][b][ci][u][v], 2646 floats
#define WS_BETA   15446    // beta[c][a][b], 18 floats
#define WS_W9     15464    // W9[c][ci][dy][dx], 486 floats
#define WS_BT     15950    // beta_tot[c] (interior combined bias), 2 floats
#define WS_INI    16384    // ini[b][c][h][w], 1,638,400 floats
#define WS_UIT    (16384 + 1638400)      // uiL[bc][l][p128] bf16, 2,097,152 ushorts
#define WS_UFT    (16384 + 2*1638400)    // ufL[bc][l][p128] bf16

typedef short bf16x8 __attribute__((ext_vector_type(8)));
typedef float f32x4  __attribute__((ext_vector_type(4)));

__device__ inline ushort f2bf(float f) {   // round-to-nearest-even
    unsigned u = __float_as_uint(f);
    unsigned r = (u + 0x7fffu + ((u >> 16) & 1u)) >> 16;
    return (ushort)r;
}

// Blocks 0..49: Mrow[r*128+p] = sum_q wl2[p,q]*wl1[q,r] (0 for p>=100).
// Block 50: composite conv weights K, beta, W9, beta_tot.
__global__ __launch_bounds__(256) void k_prep(const float* __restrict__ wl1,
                                              const float* __restrict__ wl2,
                                              const float* __restrict__ wc1,
                                              const float* __restrict__ bc1,
                                              const float* __restrict__ wc2,
                                              const float* __restrict__ bc2,
                                              float* __restrict__ ws) {
    __shared__ float swc1[9408];   // 64*3*49
    __shared__ float swc2[1152];   // 2*64*9
    __shared__ float sK[2646];
    __shared__ float sBeta[18];
    int t = threadIdx.x;
    if (blockIdx.x < 50) {
        int idx = blockIdx.x * 256 + t;    // 12800 exact
        int r = idx >> 7, p = idx & 127;
        float s = 0.f;
        if (p < 100)
            for (int q = 0; q < 200; ++q)
                s += wl2[p * 200 + q] * wl1[q * 100 + r];
        ws[WS_M + r * 128 + p] = s;
        return;
    }
    float* K    = ws + WS_K;
    float* Beta = ws + WS_BETA;
    float* W9   = ws + WS_W9;
    float* Bt   = ws + WS_BT;
    for (int i = t; i < 9408; i += 256) swc1[i] = wc1[i];
    for (int i = t; i < 1152; i += 256) swc2[i] = wc2[i];
    __syncthreads();
    for (int idx = t; idx < 2646; idx += 256) {
        int v = idx % 7; int t1 = idx / 7;
        int u = t1 % 7;  int t2 = t1 / 7;
        int ci = t2 % 3; int t3 = t2 / 3;
        int b = t3 % 3;  int t4 = t3 / 3;
        int a = t4 % 3;  int c = t4 / 3;
        float s = 0.f;
        for (int c64 = 0; c64 < 64; ++c64)
            s += swc2[((c * 64 + c64) * 3 + a) * 3 + b] *
                 swc1[((c64 * 3 + ci) * 7 + u) * 7 + v];
        sK[idx] = s; K[idx] = s;
    }
    if (t < 18) {
        int b = t % 3; int a = (t / 3) % 3; int c = t / 9;
        float s = 0.f;
        for (int c64 = 0; c64 < 64; ++c64)
            s += swc2[((c * 64 + c64) * 3 + a) * 3 + b] * bc1[c64];
        sBeta[t] = s; Beta[t] = s;
    }
    __syncthreads();
    for (int idx = t; idx < 486; idx += 256) {
        int dx = idx % 9; int t1 = idx / 9;
        int dy = t1 % 9;  int t2 = t1 / 9;
        int ci = t2 % 3;  int c = t2 / 3;
        float s = 0.f;
        for (int a = 0; a < 3; ++a) {
            int u = dy - a; if (u < 0 || u > 6) continue;
            for (int b = 0; b < 3; ++b) {
                int v = dx - b; if (v < 0 || v > 6) continue;
                s += sK[((a * 3 + b) * 3 + ci) * 49 + c * 1323 + u * 7 + v];
            }
        }
        W9[idx] = s;  // layout c*243 + ci*81 + dy*9 + dx
    }
    if (t < 2) {
        float s = bc2[t];
        for (int j = 0; j < 9; ++j) s += sBeta[t * 9 + j];
        Bt[t] = s;
    }
}

// Fused conv+border with DISJOINT writes (no block-order dependence):
// blocks [0,800) = interior 9x9 composite conv, stores ONLY non-frame pixels;
// blocks [800,5904) = wave-parallel exact border, stores ONLY the 1-px frame.
__global__ __launch_bounds__(256) void k_convborder(const float* __restrict__ x,
                                                    const float* __restrict__ bc2,
                                                    const float* __restrict__ ws,
                                                    float* __restrict__ ini) {
    __shared__ float sx[3][40][40];
    int cb = blockIdx.x;
    int t = threadIdx.x;
    if (cb < 800) {
        int gx = cb % 10, gy = (cb / 10) % 10, b = cb / 100;
        int gh0 = gy * 32, gw0 = gx * 32;
        for (int idx = t; idx < 3 * 40 * 40; idx += 256) {
            int ci = idx / 1600;
            int rem = idx - ci * 1600;
            int rr = rem / 40, cc = rem - rr * 40;
            int gh = gh0 - 4 + rr, gw = gw0 - 4 + cc;
            float v = 0.f;
            if ((unsigned)gh < 320u && (unsigned)gw < 320u)
                v = x[(b * 3 + ci) * 102400 + gh * 320 + gw];
            sx[ci][rr][cc] = v;
        }
        __syncthreads();
        const float* W9g = ws + WS_W9;   // wave-uniform addresses -> s_load
        const float* Btg = ws + WS_BT;
        int r = t >> 3, cg = t & 7;
        int h = gh0 + r, w0c = gw0 + cg * 4;
        float acc0[4], acc1[4];
        float bt0 = Btg[0], bt1 = Btg[1];
        #pragma unroll
        for (int j = 0; j < 4; ++j) { acc0[j] = bt0; acc1[j] = bt1; }
        #pragma unroll
        for (int ci = 0; ci < 3; ++ci) {
            #pragma unroll
            for (int dy = 0; dy < 9; ++dy) {
                const float* xr = &sx[ci][r + dy][cg * 4];
                float4 xa = *(const float4*)(xr);
                float4 xb = *(const float4*)(xr + 4);
                float4 xc = *(const float4*)(xr + 8);
                float xv[12] = {xa.x, xa.y, xa.z, xa.w,
                                xb.x, xb.y, xb.z, xb.w,
                                xc.x, xc.y, xc.z, xc.w};
                #pragma unroll
                for (int dx = 0; dx < 9; ++dx) {
                    float w0t = W9g[ci * 81 + dy * 9 + dx];
                    float w1t = W9g[243 + ci * 81 + dy * 9 + dx];
                    #pragma unroll
                    for (int j = 0; j < 4; ++j) {
                        acc0[j] += w0t * xv[dx + j];
                        acc1[j] += w1t * xv[dx + j];
                    }
                }
            }
        }
        // Frame pixels belong to the border path — skip them here.
        if (h == 0 || h == 319) return;
        size_t obase = (size_t)(b * 2) * 102400 + h * 320 + w0c;
        if (w0c == 0) {              // w=0 is frame: store j=1..3
            #pragma unroll
            for (int j = 1; j < 4; ++j) {
                ini[obase + j] = acc0[j];
                ini[obase + 102400 + j] = acc1[j];
            }
        } else if (w0c == 316) {     // w=319 is frame: store j=0..2
            #pragma unroll
            for (int j = 0; j < 3; ++j) {
                ini[obase + j] = acc0[j];
                ini[obase + 102400 + j] = acc1[j];
            }
        } else {
            *(float4*)&ini[obase] = make_float4(acc0[0], acc0[1], acc0[2], acc0[3]);
            *(float4*)&ini[obase + 102400] = make_float4(acc1[0], acc1[1], acc1[2], acc1[3]);
        }
        return;
    }
    // ---- border path (owns the 1-px frame exclusively) ----
    int wid  = ((cb - 800) * 256 + t) >> 6;   // 0..20415 exact
    int lane = t & 63;
    int c = wid & 1, pi = wid >> 1;
    int b = pi / 1276, j = pi % 1276;
    int h, w;
    if (j < 320)      { h = 0;           w = j; }
    else if (j < 640) { h = 319;         w = j - 320; }
    else if (j < 958) { h = 1 + j - 640; w = 0; }
    else              { h = 1 + j - 958; w = 319; }
    const float* K    = ws + WS_K;
    const float* Beta = ws + WS_BETA;
    float acc = 0.f;
    #pragma unroll
    for (int rep = 0; rep < 3; ++rep) {
        int e = lane + rep * 64;
        if (e < 189) {
            int a = e / 63;   int rem  = e - a * 63;
            int bb = rem / 21; int rem2 = rem - bb * 21;
            int ci = rem2 / 7; int u = rem2 - ci * 7;
            int hh0 = h + a - 1;
            int ww0 = w + bb - 1;
            bool abv = ((unsigned)hh0 < 320u) & ((unsigned)ww0 < 320u);
            if (abv && ci == 0 && u == 0) acc += Beta[c * 9 + a * 3 + bb];
            int hx = hh0 + u - 3;
            if (abv && (unsigned)hx < 320u) {
                const float* Kc = K + ((a * 3 + bb) * 3 + ci) * 49 + c * 1323 + u * 7;
                const float* xr = x + (b * 3 + ci) * 102400 + hx * 320;
                #pragma unroll
                for (int v = 0; v < 7; ++v) {
                    int wx = ww0 + v - 3;
                    if ((unsigned)wx < 320u)
                        acc += Kc[v] * xr[wx];
                }
            }
        }
    }
    #pragma unroll
    for (int off = 32; off > 0; off >>= 1)
        acc += __shfl_down(acc, off, 64);
    if (lane == 0)
        ini[(b * 2 + c) * 102400 + h * 320 + w] = acc + bc2[c];
}

// trans (both modes): outL[bc][l][p128] = relu(sum_r M[p][r]*patch[l][r]) in bf16.
// Block: 64 l-lanes x 4 waves; wave owns 32-wide p-chunk (M zero-padded to 128,
// so p>=100 stores zeros for free). M read via wave-uniform global (K$/s_load);
// LDS holds only the patch strip sP.
#define SPS 68
__global__ __launch_bounds__(256) void k_trans(const float* __restrict__ ini,
                                               const float* __restrict__ x,
                                               const float* __restrict__ wfm,
                                               const float* __restrict__ bfm,
                                               const float* __restrict__ ws,
                                               ushort* __restrict__ uiL,
                                               ushort* __restrict__ ufL) {
    __shared__ float sP[100 * SPS];   // sP[r*SPS + li]
    int bc = blockIdx.x;     // 0..15
    int lg = blockIdx.y;     // 0..15 -> 64 patches (2 patch-rows x 32)
    int mode = blockIdx.z;   // 0: ini, 1: fea(x)
    int t = threadIdx.x;
    int b = bc >> 1, c = bc & 1;
    int row0 = lg * 20;      // image-row base of this block's strip
    float wf0 = 0.f, wf1 = 0.f, wf2 = 0.f, bf = 0.f;
    if (mode == 1) { wf0 = wfm[c * 3 + 0]; wf1 = wfm[c * 3 + 1]; wf2 = wfm[c * 3 + 2]; bf = bfm[c]; }
    for (int e = t; e < 6400; e += 256) {
        int irow = e / 320, col = e % 320;
        int off = (row0 + irow) * 320 + col;
        float val;
        if (mode == 0) {
            val = ini[bc * 102400 + off];
        } else {
            val = (bf + x[(b * 3 + 0) * 102400 + off] * wf0
                      + x[(b * 3 + 1) * 102400 + off] * wf1
                      + x[(b * 3 + 2) * 102400 + off] * wf2) * 0.25f;
        }
        int li = (irow / 10) * 32 + col / 10;
        int r  = (irow % 10) * 10 + col % 10;
        sP[r * SPS + li] = val;
    }
    __syncthreads();
    int lane = t & 63;
    int wave = __builtin_amdgcn_readfirstlane(t >> 6);
    int p0 = wave * 32;
    const float* Mg = ws + WS_M;
    float acc[32];
    #pragma unroll
    for (int k = 0; k < 32; ++k) acc[k] = 0.f;
    for (int r = 0; r < 100; ++r) {
        float pv = sP[r * SPS + lane];
        const float4* Mr = (const float4*)(Mg + r * 128 + p0);  // wave-uniform
        #pragma unroll
        for (int g = 0; g < 8; ++g) {
            float4 m = Mr[g];
            acc[g * 4 + 0] += m.x * pv;
            acc[g * 4 + 1] += m.y * pv;
            acc[g * 4 + 2] += m.z * pv;
            acc[g * 4 + 3] += m.w * pv;
        }
    }
    ushort* outL = (mode == 0) ? uiL : ufL;
    ushort* orow = outL + ((size_t)bc * 1024 + lg * 64 + lane) * 128 + p0;
    #pragma unroll
    for (int k = 0; k < 32; k += 2) {
        unsigned v0 = f2bf(fmaxf(acc[k], 0.f));
        unsigned v1 = f2bf(fmaxf(acc[k + 1], 0.f));
        *(unsigned*)&orow[k] = v0 | (v1 << 16);
    }
}

// att[bc][l][m] = (1/100) * sum_p ui[l][p]*uf[m][p], bf16 MFMA 16x16x32.
// 128x128 tile/block, 4 waves 2x2, each wave 64x64 = 4x4 mfma tiles.
__global__ __launch_bounds__(256) void k_att(const ushort* __restrict__ ui,
                                             const ushort* __restrict__ uf,
                                             float* __restrict__ out) {
    int bc   = blockIdx.z;
    int row0 = blockIdx.y * 128, col0 = blockIdx.x * 128;
    int wave = threadIdx.x >> 6, lane = threadIdx.x & 63;
    int r0 = row0 + (wave >> 1) * 64;
    int c0 = col0 + (wave & 1) * 64;
    int m = lane & 15, quad = lane >> 4;
    const ushort* ub = ui + (size_t)bc * 1024 * 128;
    const ushort* vb = uf + (size_t)bc * 1024 * 128;
    f32x4 acc[4][4];
    #pragma unroll
    for (int i = 0; i < 4; ++i)
        #pragma unroll
        for (int j = 0; j < 4; ++j)
            acc[i][j] = (f32x4){0.f, 0.f, 0.f, 0.f};
    #pragma unroll
    for (int k0 = 0; k0 < 128; k0 += 32) {
        bf16x8 af[4], bfr[4];
        #pragma unroll
        for (int i = 0; i < 4; ++i)
            af[i] = *(const bf16x8*)&ub[(size_t)(r0 + i * 16 + m) * 128 + k0 + quad * 8];
        #pragma unroll
        for (int j = 0; j < 4; ++j)
            bfr[j] = *(const bf16x8*)&vb[(size_t)(c0 + j * 16 + m) * 128 + k0 + quad * 8];
        #pragma unroll
        for (int i = 0; i < 4; ++i)
            #pragma unroll
            for (int j = 0; j < 4; ++j)
                acc[i][j] = __builtin_amdgcn_mfma_f32_16x16x32_bf16(af[i], bfr[j], acc[i][j], 0, 0, 0);
    }
    // C/D: col = lane&15, row = quad*4 + reg (m89/m91-verified)
    #pragma unroll
    for (int i = 0; i < 4; ++i) {
        #pragma unroll
        for (int r = 0; r < 4; ++r) {
            int row = r0 + i * 16 + quad * 4 + r;
            float* o = out + ((size_t)bc * 1024 + row) * 1024;
            #pragma unroll
            for (int j = 0; j < 4; ++j)
                o[c0 + j * 16 + m] = acc[i][j][r] * 0.01f;
        }
    }
}

extern "C" void kernel_launch(void* const* d_in, const int* in_sizes, int n_in,
                              void* d_out, int out_size, void* d_ws, size_t ws_size,
                              hipStream_t stream) {
    const float* x       = (const float*)d_in[0];
    const float* w_conv1 = (const float*)d_in[1];
    const float* b_conv1 = (const float*)d_in[2];
    const float* w_conv2 = (const float*)d_in[3];
    const float* b_conv2 = (const float*)d_in[4];
    const float* w_fm    = (const float*)d_in[5];
    const float* b_fm    = (const float*)d_in[6];
    const float* w_lin1  = (const float*)d_in[7];
    const float* w_lin2  = (const float*)d_in[8];
    float* out = (float*)d_out;
    float* ws  = (float*)d_ws;
    ushort* uiL = (ushort*)(ws + WS_UIT);
    ushort* ufL = (ushort*)(ws + WS_UFT);

    k_prep<<<51, 256, 0, stream>>>(w_lin1, w_lin2, w_conv1, b_conv1, w_conv2, b_conv2, ws);
    k_convborder<<<5904, 256, 0, stream>>>(x, b_conv2, ws, ws + WS_INI);
    k_trans<<<dim3(16, 16, 2), 256, 0, stream>>>(ws + WS_INI, x, w_fm, b_fm, ws, uiL, ufL);
    k_att<<<dim3(8, 8, 16), 256, 0, stream>>>(uiL, ufL, out);
}

// Round 8
// 255.110 us; speedup vs baseline: 1.0762x; 1.0762x over previous
//
#include <hip/hip_runtime.h>

// Workspace layout (float offsets)
#define WS_M      0        // Mrow[r*128+p] = M[p][r] (p-padded 100->128 w/ zeros), 12800 floats
#define WS_K      12800    // K[c][a][b][ci][u][v], 2646 floats
#define WS_BETA   15446    // beta[c][a][b], 18 floats
#define WS_W9     15464    // W9[c][ci][dy][dx], 486 floats
#define WS_BT     15950    // beta_tot[c] (interior combined bias), 2 floats
#define WS_INI    16384    // ini[b][c][h][w], 1,638,400 floats
#define WS_UIT    (16384 + 1638400)      // uiL[bc][l][p128] bf16, 2,097,152 ushorts
#define WS_UFT    (16384 + 2*1638400)    // ufL[bc][l][p128] bf16

typedef short bf16x8 __attribute__((ext_vector_type(8)));
typedef float f32x4  __attribute__((ext_vector_type(4)));

__device__ inline ushort f2bf(float f) {   // round-to-nearest-even
    unsigned u = __float_as_uint(f);
    unsigned r = (u + 0x7fffu + ((u >> 16) & 1u)) >> 16;
    return (ushort)r;
}

// Blocks 0..49: Mrow[r*128+p] = sum_q wl2[p,q]*wl1[q,r] (0 for p>=100).
// Block 50: composite conv weights K, beta, W9, beta_tot.
__global__ __launch_bounds__(256) void k_prep(const float* __restrict__ wl1,
                                              const float* __restrict__ wl2,
                                              const float* __restrict__ wc1,
                                              const float* __restrict__ bc1,
                                              const float* __restrict__ wc2,
                                              const float* __restrict__ bc2,
                                              float* __restrict__ ws) {
    __shared__ float swc1[9408];   // 64*3*49
    __shared__ float swc2[1152];   // 2*64*9
    __shared__ float sK[2646];
    __shared__ float sBeta[18];
    int t = threadIdx.x;
    if (blockIdx.x < 50) {
        int idx = blockIdx.x * 256 + t;    // 12800 exact
        int r = idx >> 7, p = idx & 127;
        float s = 0.f;
        if (p < 100)
            for (int q = 0; q < 200; ++q)
                s += wl2[p * 200 + q] * wl1[q * 100 + r];
        ws[WS_M + r * 128 + p] = s;
        return;
    }
    float* K    = ws + WS_K;
    float* Beta = ws + WS_BETA;
    float* W9   = ws + WS_W9;
    float* Bt   = ws + WS_BT;
    for (int i = t; i < 9408; i += 256) swc1[i] = wc1[i];
    for (int i = t; i < 1152; i += 256) swc2[i] = wc2[i];
    __syncthreads();
    for (int idx = t; idx < 2646; idx += 256) {
        int v = idx % 7; int t1 = idx / 7;
        int u = t1 % 7;  int t2 = t1 / 7;
        int ci = t2 % 3; int t3 = t2 / 3;
        int b = t3 % 3;  int t4 = t3 / 3;
        int a = t4 % 3;  int c = t4 / 3;
        float s = 0.f;
        for (int c64 = 0; c64 < 64; ++c64)
            s += swc2[((c * 64 + c64) * 3 + a) * 3 + b] *
                 swc1[((c64 * 3 + ci) * 7 + u) * 7 + v];
        sK[idx] = s; K[idx] = s;
    }
    if (t < 18) {
        int b = t % 3; int a = (t / 3) % 3; int c = t / 9;
        float s = 0.f;
        for (int c64 = 0; c64 < 64; ++c64)
            s += swc2[((c * 64 + c64) * 3 + a) * 3 + b] * bc1[c64];
        sBeta[t] = s; Beta[t] = s;
    }
    __syncthreads();
    for (int idx = t; idx < 486; idx += 256) {
        int dx = idx % 9; int t1 = idx / 9;
        int dy = t1 % 9;  int t2 = t1 / 9;
        int ci = t2 % 3;  int c = t2 / 3;
        float s = 0.f;
        for (int a = 0; a < 3; ++a) {
            int u = dy - a; if (u < 0 || u > 6) continue;
            for (int b = 0; b < 3; ++b) {
                int v = dx - b; if (v < 0 || v > 6) continue;
                s += sK[((a * 3 + b) * 3 + ci) * 49 + c * 1323 + u * 7 + v];
            }
        }
        W9[idx] = s;  // layout c*243 + ci*81 + dy*9 + dx
    }
    if (t < 2) {
        float s = bc2[t];
        for (int j = 0; j < 9; ++j) s += sBeta[t * 9 + j];
        Bt[t] = s;
    }
}

// Interior 9x9 composite conv, 32x32 tile/block, LDS 40x40x3 (stride 40:
// b128 collisions 2-way). Stores ONLY non-frame pixels (disjoint from k_border).
__global__ __launch_bounds__(256) void k_conv(const float* __restrict__ x,
                                              const float* __restrict__ ws,
                                              float* __restrict__ ini) {
    __shared__ float sx[3][40][40];
    int b   = blockIdx.z;
    int gh0 = blockIdx.y * 32, gw0 = blockIdx.x * 32;
    int t = threadIdx.x;
    for (int idx = t; idx < 3 * 40 * 40; idx += 256) {
        int ci = idx / 1600;
        int rem = idx - ci * 1600;
        int rr = rem / 40, cc = rem - rr * 40;
        int gh = gh0 - 4 + rr, gw = gw0 - 4 + cc;
        float v = 0.f;
        if ((unsigned)gh < 320u && (unsigned)gw < 320u)
            v = x[(b * 3 + ci) * 102400 + gh * 320 + gw];
        sx[ci][rr][cc] = v;
    }
    __syncthreads();
    const float* W9g = ws + WS_W9;   // wave-uniform addresses -> s_load
    const float* Btg = ws + WS_BT;
    int r = t >> 3, cg = t & 7;
    int h = gh0 + r, w0c = gw0 + cg * 4;
    float acc0[4], acc1[4];
    float bt0 = Btg[0], bt1 = Btg[1];
    #pragma unroll
    for (int j = 0; j < 4; ++j) { acc0[j] = bt0; acc1[j] = bt1; }
    #pragma unroll
    for (int ci = 0; ci < 3; ++ci) {
        #pragma unroll
        for (int dy = 0; dy < 9; ++dy) {
            const float* xr = &sx[ci][r + dy][cg * 4];
            float4 xa = *(const float4*)(xr);
            float4 xb = *(const float4*)(xr + 4);
            float4 xc = *(const float4*)(xr + 8);
            float xv[12] = {xa.x, xa.y, xa.z, xa.w,
                            xb.x, xb.y, xb.z, xb.w,
                            xc.x, xc.y, xc.z, xc.w};
            #pragma unroll
            for (int dx = 0; dx < 9; ++dx) {
                float w0t = W9g[ci * 81 + dy * 9 + dx];
                float w1t = W9g[243 + ci * 81 + dy * 9 + dx];
                #pragma unroll
                for (int j = 0; j < 4; ++j) {
                    acc0[j] += w0t * xv[dx + j];
                    acc1[j] += w1t * xv[dx + j];
                }
            }
        }
    }
    if (h == 0 || h == 319) return;   // frame rows owned by k_border
    size_t obase = (size_t)(b * 2) * 102400 + h * 320 + w0c;
    if (w0c == 0) {                   // w=0 is frame: store j=1..3
        #pragma unroll
        for (int j = 1; j < 4; ++j) {
            ini[obase + j] = acc0[j];
            ini[obase + 102400 + j] = acc1[j];
        }
    } else if (w0c == 316) {          // w=319 is frame: store j=0..2
        #pragma unroll
        for (int j = 0; j < 3; ++j) {
            ini[obase + j] = acc0[j];
            ini[obase + 102400 + j] = acc1[j];
        }
    } else {
        *(float4*)&ini[obase] = make_float4(acc0[0], acc0[1], acc0[2], acc0[3]);
        *(float4*)&ini[obase + 102400] = make_float4(acc1[0], acc1[1], acc1[2], acc1[3]);
    }
}

// Exact border, wave-parallel: one WAVE per (border pixel, out-channel).
// Owns the 1-px frame exclusively.
__global__ __launch_bounds__(256) void k_border(const float* __restrict__ x,
                                                const float* __restrict__ bc2,
                                                const float* __restrict__ ws,
                                                float* __restrict__ ini) {
    int wid  = (blockIdx.x * 256 + threadIdx.x) >> 6;   // 0..20415 (grid exact)
    int lane = threadIdx.x & 63;
    int c = wid & 1, pi = wid >> 1;
    int b = pi / 1276, j = pi % 1276;
    int h, w;
    if (j < 320)      { h = 0;           w = j; }
    else if (j < 640) { h = 319;         w = j - 320; }
    else if (j < 958) { h = 1 + j - 640; w = 0; }
    else              { h = 1 + j - 958; w = 319; }
    const float* K    = ws + WS_K;
    const float* Beta = ws + WS_BETA;
    float acc = 0.f;
    #pragma unroll
    for (int rep = 0; rep < 3; ++rep) {
        int e = lane + rep * 64;
        if (e < 189) {
            int a = e / 63;   int rem  = e - a * 63;
            int bb = rem / 21; int rem2 = rem - bb * 21;
            int ci = rem2 / 7; int u = rem2 - ci * 7;
            int hh0 = h + a - 1;
            int ww0 = w + bb - 1;
            bool abv = ((unsigned)hh0 < 320u) & ((unsigned)ww0 < 320u);
            if (abv && ci == 0 && u == 0) acc += Beta[c * 9 + a * 3 + bb];
            int hx = hh0 + u - 3;
            if (abv && (unsigned)hx < 320u) {
                const float* Kc = K + ((a * 3 + bb) * 3 + ci) * 49 + c * 1323 + u * 7;
                const float* xr = x + (b * 3 + ci) * 102400 + hx * 320;
                #pragma unroll
                for (int v = 0; v < 7; ++v) {
                    int wx = ww0 + v - 3;
                    if ((unsigned)wx < 320u)
                        acc += Kc[v] * xr[wx];
                }
            }
        }
    }
    #pragma unroll
    for (int off = 32; off > 0; off >>= 1)
        acc += __shfl_down(acc, off, 64);
    if (lane == 0)
        ini[(b * 2 + c) * 102400 + h * 320 + w] = acc + bc2[c];
}

// trans (both modes): outL[bc][l][p128] = relu(sum_r M[p][r]*patch[l][r]) in bf16.
// Block: 64 l-lanes x 4 waves; wave owns 32-wide p-chunk (M zero-padded to 128,
// so p>=100 stores zeros for free). M read via wave-uniform global (K$/s_load);
// LDS holds only the patch strip sP.
#define SPS 68
__global__ __launch_bounds__(256) void k_trans(const float* __restrict__ ini,
                                               const float* __restrict__ x,
                                               const float* __restrict__ wfm,
                                               const float* __restrict__ bfm,
                                               const float* __restrict__ ws,
                                               ushort* __restrict__ uiL,
                                               ushort* __restrict__ ufL) {
    __shared__ float sP[100 * SPS];   // sP[r*SPS + li]
    int bc = blockIdx.x;     // 0..15
    int lg = blockIdx.y;     // 0..15 -> 64 patches (2 patch-rows x 32)
    int mode = blockIdx.z;   // 0: ini, 1: fea(x)
    int t = threadIdx.x;
    int b = bc >> 1, c = bc & 1;
    int row0 = lg * 20;      // image-row base of this block's strip
    float wf0 = 0.f, wf1 = 0.f, wf2 = 0.f, bf = 0.f;
    if (mode == 1) { wf0 = wfm[c * 3 + 0]; wf1 = wfm[c * 3 + 1]; wf2 = wfm[c * 3 + 2]; bf = bfm[c]; }
    for (int e = t; e < 6400; e += 256) {
        int irow = e / 320, col = e % 320;
        int off = (row0 + irow) * 320 + col;
        float val;
        if (mode == 0) {
            val = ini[bc * 102400 + off];
        } else {
            val = (bf + x[(b * 3 + 0) * 102400 + off] * wf0
                      + x[(b * 3 + 1) * 102400 + off] * wf1
                      + x[(b * 3 + 2) * 102400 + off] * wf2) * 0.25f;
        }
        int li = (irow / 10) * 32 + col / 10;
        int r  = (irow % 10) * 10 + col % 10;
        sP[r * SPS + li] = val;
    }
    __syncthreads();
    int lane = t & 63;
    int wave = __builtin_amdgcn_readfirstlane(t >> 6);
    int p0 = wave * 32;
    const float* Mg = ws + WS_M;
    float acc[32];
    #pragma unroll
    for (int k = 0; k < 32; ++k) acc[k] = 0.f;
    for (int r = 0; r < 100; ++r) {
        float pv = sP[r * SPS + lane];
        const float4* Mr = (const float4*)(Mg + r * 128 + p0);  // wave-uniform
        #pragma unroll
        for (int g = 0; g < 8; ++g) {
            float4 m = Mr[g];
            acc[g * 4 + 0] += m.x * pv;
            acc[g * 4 + 1] += m.y * pv;
            acc[g * 4 + 2] += m.z * pv;
            acc[g * 4 + 3] += m.w * pv;
        }
    }
    ushort* outL = (mode == 0) ? uiL : ufL;
    ushort* orow = outL + ((size_t)bc * 1024 + lg * 64 + lane) * 128 + p0;
    #pragma unroll
    for (int k = 0; k < 32; k += 2) {
        unsigned v0 = f2bf(fmaxf(acc[k], 0.f));
        unsigned v1 = f2bf(fmaxf(acc[k + 1], 0.f));
        *(unsigned*)&orow[k] = v0 | (v1 << 16);
    }
}

// att[bc][l][m] = (1/100) * sum_p ui[l][p]*uf[m][p], bf16 MFMA 16x16x32.
// 128x128 tile/block, 4 waves 2x2, each wave 64x64 = 4x4 mfma tiles.
__global__ __launch_bounds__(256) void k_att(const ushort* __restrict__ ui,
                                             const ushort* __restrict__ uf,
                                             float* __restrict__ out) {
    int bc   = blockIdx.z;
    int row0 = blockIdx.y * 128, col0 = blockIdx.x * 128;
    int wave = threadIdx.x >> 6, lane = threadIdx.x & 63;
    int r0 = row0 + (wave >> 1) * 64;
    int c0 = col0 + (wave & 1) * 64;
    int m = lane & 15, quad = lane >> 4;
    const ushort* ub = ui + (size_t)bc * 1024 * 128;
    const ushort* vb = uf + (size_t)bc * 1024 * 128;
    f32x4 acc[4][4];
    #pragma unroll
    for (int i = 0; i < 4; ++i)
        #pragma unroll
        for (int j = 0; j < 4; ++j)
            acc[i][j] = (f32x4){0.f, 0.f, 0.f, 0.f};
    #pragma unroll
    for (int k0 = 0; k0 < 128; k0 += 32) {
        bf16x8 af[4], bfr[4];
        #pragma unroll
        for (int i = 0; i < 4; ++i)
            af[i] = *(const bf16x8*)&ub[(size_t)(r0 + i * 16 + m) * 128 + k0 + quad * 8];
        #pragma unroll
        for (int j = 0; j < 4; ++j)
            bfr[j] = *(const bf16x8*)&vb[(size_t)(c0 + j * 16 + m) * 128 + k0 + quad * 8];
        #pragma unroll
        for (int i = 0; i < 4; ++i)
            #pragma unroll
            for (int j = 0; j < 4; ++j)
                acc[i][j] = __builtin_amdgcn_mfma_f32_16x16x32_bf16(af[i], bfr[j], acc[i][j], 0, 0, 0);
    }
    // C/D: col = lane&15, row = quad*4 + reg (m89/m91-verified)
    #pragma unroll
    for (int i = 0; i < 4; ++i) {
        #pragma unroll
        for (int r = 0; r < 4; ++r) {
            int row = r0 + i * 16 + quad * 4 + r;
            float* o = out + ((size_t)bc * 1024 + row) * 1024;
            #pragma unroll
            for (int j = 0; j < 4; ++j)
                o[c0 + j * 16 + m] = acc[i][j][r] * 0.01f;
        }
    }
}

extern "C" void kernel_launch(void* const* d_in, const int* in_sizes, int n_in,
                              void* d_out, int out_size, void* d_ws, size_t ws_size,
                              hipStream_t stream) {
    const float* x       = (const float*)d_in[0];
    const float* w_conv1 = (const float*)d_in[1];
    const float* b_conv1 = (const float*)d_in[2];
    const float* w_conv2 = (const float*)d_in[3];
    const float* b_conv2 = (const float*)d_in[4];
    const float* w_fm    = (const float*)d_in[5];
    const float* b_fm    = (const float*)d_in[6];
    const float* w_lin1  = (const float*)d_in[7];
    const float* w_lin2  = (const float*)d_in[8];
    float* out = (float*)d_out;
    float* ws  = (float*)d_ws;
    ushort* uiL = (ushort*)(ws + WS_UIT);
    ushort* ufL = (ushort*)(ws + WS_UFT);

    k_prep<<<51, 256, 0, stream>>>(w_lin1, w_lin2, w_conv1, b_conv1, w_conv2, b_conv2, ws);
    k_conv<<<dim3(10, 10, 8), 256, 0, stream>>>(x, ws, ws + WS_INI);
    k_border<<<5104, 256, 0, stream>>>(x, b_conv2, ws, ws + WS_INI);  // 20416 waves
    k_trans<<<dim3(16, 16, 2), 256, 0, stream>>>(ws + WS_INI, x, w_fm, b_fm, ws, uiL, ufL);
    k_att<<<dim3(8, 8, 16), 256, 0, stream>>>(uiL, ufL, out);
}